// Round 3
// baseline (114.058 us; speedup 1.0000x reference)
//
#include <hip/hip_runtime.h>
#include <math.h>

namespace {
constexpr int B = 64, A = 5, H = 52, W = 52, T = 50;
constexpr int HW = H * W;        // 2704
constexpr int N = A * HW;        // 13520
constexpr int CH2 = 2 * A * HW;  // 27040 (per-batch xy/wh/weight span)
constexpr float POS_THRESH_F = 0.6f;
constexpr float EPS_F = 1e-5f;

// d_out layout: t_xy, t_wh, t_xywh_weight, t_o_obj, t_o_noobj, t_label (flat, f32)
constexpr long O_XY = 0;
constexpr long O_WH = (long)B * CH2;
constexpr long O_WT = 2L * B * CH2;
constexpr long O_OBJ = 3L * B * CH2;
constexpr long O_NOOBJ = O_OBJ + (long)B * N;
constexpr long O_LABEL = O_NOOBJ + (long)B * N;

// d_ws layout: float4 box[B*T] {tl,tt,tr,tb}, then float ta375[B*T]
constexpr long WS_TA = (long)B * T * 4;  // in floats
}  // namespace

// Kernel 0: precompute truth-box edges + 0.375*area into workspace.
// Bit-exact same formulas as the validated round-1/2 LDS staging.
__global__ __launch_bounds__(256) void region_k0(
    const float* __restrict__ truth, float* __restrict__ ws) {
#pragma clang fp contract(off)
  const int idx = blockIdx.x * 256 + threadIdx.x;
  if (idx >= B * T) return;
  const float* t5 = truth + (long)idx * 5;
  const float tx = t5[0], ty = t5[1], tw = t5[2], th = t5[3];
  float4* box = (float4*)ws;
  box[idx] = make_float4(tx - tw * 0.5f, ty - th * 0.5f,
                         tx + tw * 0.5f, ty + th * 0.5f);
  const float ta = tw * th;
  ws[WS_TA + idx] = 0.375f * ta;
}

// Kernel 1: per predicted box, "any IoU > 0.6?" over 50 truths -> t_o_noobj
// mask; also writes the base values of all six outputs.
// Truth data is wave-uniform (depends only on blockIdx.y + loop counter) and
// is read from the k0 workspace through the scalar-memory pipe — no LDS.
// Division-free test (iou>0.6 <=> ov>0.375*(barea+ta)) with a conservative
// tolerance band; band-threads rerun the exact IEEE-division loop so boundary
// decisions are bit-identical to the reference (validated absmax 0.0).
__global__ __launch_bounds__(256) void region_k1(
    const float* __restrict__ xy, const float* __restrict__ wh,
    const float* __restrict__ obj, const float* __restrict__ truth,
    const float* __restrict__ biases, const float* __restrict__ ws,
    float* __restrict__ out) {
#pragma clang fp contract(off)
  const int b = blockIdx.y;
  const int tid = threadIdx.x;
  const int n = blockIdx.x * 256 + tid;
  if (n >= N) return;
  const int a = n / HW;
  const int r = n - a * HW;
  const int h = r / W;
  const int w = r - h * W;
  const long pb = (long)b * CH2;
  const long ix = pb + (long)a * HW + r;  // channel a (x / w-part)
  const long iy = ix + (long)A * HW;      // channel a+A (y / h-part)
  const float x = xy[ix], y = xy[iy];
  const float wx = wh[ix], wyv = wh[iy];
  const long io = (long)b * N + n;
  const float objv = obj[io];
  // box center/size — mirror reference f32 op order exactly
  const float bx = (x + (float)w) / (float)W;
  const float by = (y + (float)h) / (float)H;
  const float bw = expf(wx) * biases[2 * a] / (float)W;
  const float bh = expf(wyv) * biases[2 * a + 1] / (float)H;
  const float bl = bx - bw * 0.5f, brr = bx + bw * 0.5f;
  const float bt = by - bh * 0.5f, bbt = by + bh * 0.5f;
  const float barea = bw * bh;
  const float tb375 = 0.375f * barea;
  // wave-uniform truth pointers (scalar loads)
  const float4* __restrict__ pbox = ((const float4*)ws) + b * T;
  const float* __restrict__ pta = ws + WS_TA + b * T;
  bool hit = false, nearb = false;
#pragma unroll 10
  for (int t = 0; t < T; ++t) {
    const float4 b4 = pbox[t];
    const float ta375 = pta[t];
    float ow = fminf(brr, b4.z) - fmaxf(bl, b4.x);
    float oh = fminf(bbt, b4.w) - fmaxf(bt, b4.y);
    ow = fmaxf(ow, 0.0f);
    oh = fmaxf(oh, 0.0f);
    const float ov = ow * oh;
    const float rhs = tb375 + ta375;     // 0.375*(barea+ta) (approx)
    const float dd = ov - rhs;
    const float tol = 2.6667e-5f * rhs;  // ~1e-5 * (barea+ta): >>2ulp band
    hit = hit || (dd > tol);
    nearb = nearb || (fabsf(dd) <= tol);
  }
  if (nearb && !hit) {
    // exact fallback — identical op sequence to the reference
    float m = -INFINITY;
    for (int t = 0; t < T; ++t) {
      const float4 b4 = pbox[t];
      const float* t5 = truth + ((long)b * T + t) * 5;
      const float ta = t5[2] * t5[3];
      float ow = fminf(brr, b4.z) - fmaxf(bl, b4.x);
      float oh = fminf(bbt, b4.w) - fmaxf(bt, b4.y);
      ow = fmaxf(ow, 0.0f);
      oh = fmaxf(oh, 0.0f);
      const float ov = ow * oh;
      const float iou = ov / ((barea + ta) - ov);
      m = fmaxf(m, iou);
    }
    hit = m > POS_THRESH_F;
  }
  out[O_NOOBJ + io] = hit ? objv : 0.0f;
  out[O_OBJ + io] = objv;
  out[O_LABEL + io] = -1.0f;
  out[O_XY + ix] = x;
  out[O_XY + iy] = y;
  out[O_WH + ix] = wx;
  out[O_WH + iy] = wyv;
  out[O_WT + ix] = 0.0f;
  out[O_WT + iy] = 0.0f;
}

// Kernel 2: per-batch truth scatters with exact JAX .at[] semantics:
//  - negative index (-1) wraps to the last element (JAX normalizes before drop)
//  - lin1 with channel 2*tn+A >= 2A is genuinely OOB -> dropped
//  - duplicate targets: last write (ascending t, lin0-scatter before
//    lin1-scatter) wins — parallel "am I the last writer?" checks.
__global__ __launch_bounds__(128) void region_k2(
    const float* __restrict__ xy, const float* __restrict__ wh,
    const float* __restrict__ obj, const float* __restrict__ truth,
    const float* __restrict__ biases, float* __restrict__ out) {
#pragma clang fp contract(off)
  __shared__ float s_vx[T], s_vy[T], s_vw[T], s_vh[T], s_vwt[T];
  __shared__ float s_vobj[T], s_vnoobj[T], s_cls[T];
  __shared__ int s_cell[T], s_eff[T], s_lin0[T], s_lin1[T], s_tn[T], s_win[T];
  __shared__ int s_tgt2[2 * T];  // xy/wh/wt-plane scatter sequence (-2 = drop)
  __shared__ int s_tgtO[T];      // obj-plane scatter sequence
  const int b = blockIdx.x;
  const int t = threadIdx.x;
  if (t < T) {
    const float* t5 = truth + ((long)b * T + t) * 5;
    const float tx = t5[0], ty = t5[1], tw = t5[2], th = t5[3];
    s_cls[t] = t5[4];
    int ti = (int)(tx * (float)W);  // trunc, matches astype(int32)
    int tj = (int)(ty * (float)H);
    int tn = 0;
    float best = -INFINITY;
    for (int aa = 0; aa < A; ++aa) {
      const float bwa = biases[2 * aa] / (float)W;
      const float bha = biases[2 * aa + 1] / (float)H;
      const float num = fminf(tw, bwa) * fminf(th, bha);
      const float den = fmaxf(tw, bwa) * fmaxf(th, bha) + EPS_F;
      const float rr = num / den;
      if (rr > best) { best = rr; tn = aa; }  // first-max, like jnp.argmax
    }
    if (tw <= EPS_F || th <= EPS_F) { ti = -1; tj = -1; tn = -1; }
    const bool valid = ti >= 0;
    const int cell = valid ? (tn * H + tj) * W + ti : -1;
    s_cell[t] = cell;
    s_eff[t] = valid ? cell : (N - 1);  // -1 wraps to N-1 in winner scatter
    const int nc = tn < 0 ? 0 : tn, jc = tj < 0 ? 0 : tj, ic = ti < 0 ? 0 : ti;
    s_tn[t] = tn;
    s_lin0[t] = (2 * tn * H + tj) * W + ti;        // only used when win
    s_lin1[t] = ((2 * tn + A) * H + tj) * W + ti;  // only used when win
    s_vx[t] = tx * (float)W - (float)ic;
    s_vy[t] = ty * (float)H - (float)jc;
    s_vw[t] = logf(fmaxf(tw * (float)W / biases[2 * nc], 1e-12f));
    s_vh[t] = logf(fmaxf(th * (float)H / biases[2 * nc + 1], 1e-12f));
    s_vwt[t] = 2.0f - tw * th;  // COORD_SCALE = 1
    // v_obj = IoU of predicted box at (nc,jc,ic) vs this truth (RESCORE)
    const long rr2 = (long)nc * HW + (long)jc * W + ic;
    const long pb = (long)b * CH2;
    const float x = xy[pb + rr2], y = xy[pb + (long)A * HW + rr2];
    const float wx = wh[pb + rr2], wyv = wh[pb + (long)A * HW + rr2];
    s_vnoobj[t] = obj[(long)b * N + rr2];
    const float bx = (x + (float)ic) / (float)W;
    const float by = (y + (float)jc) / (float)H;
    const float bw = expf(wx) * biases[2 * nc] / (float)W;
    const float bh = expf(wyv) * biases[2 * nc + 1] / (float)H;
    float ow = fminf(bx + bw * 0.5f, tx + tw * 0.5f) -
               fmaxf(bx - bw * 0.5f, tx - tw * 0.5f);
    float oh = fminf(by + bh * 0.5f, ty + th * 0.5f) -
               fmaxf(by - bh * 0.5f, ty - th * 0.5f);
    ow = fmaxf(ow, 0.0f);
    oh = fmaxf(oh, 0.0f);
    const float ov = ow * oh;
    s_vobj[t] = ov / (((bw * bh) + tw * th) - ov);
  }
  __syncthreads();
  if (t < T) {
    int winf = 0;
    if (s_cell[t] >= 0) {  // valid
      winf = 1;
      for (int u = t + 1; u < T; ++u)
        if (s_eff[u] == s_cell[t]) { winf = 0; break; }  // higher t wins
    }
    s_win[t] = winf;
  }
  __syncthreads();
  if (t < T) {
    const int J = CH2 - 1;  // wrapped target of index -1 in 2A*H*W space
    int tgt0, tgt1;
    if (s_win[t]) {
      tgt0 = s_lin0[t];
      tgt1 = (2 * s_tn[t] + A < 2 * A) ? s_lin1[t] : -2;  // OOB -> dropped
    } else {
      tgt0 = J;  // -1 wraps
      tgt1 = J;
    }
    s_tgt2[t] = tgt0;
    s_tgt2[T + t] = tgt1;
    s_tgtO[t] = s_win[t] ? s_cell[t] : (N - 1);
  }
  __syncthreads();
  // xy/wh/wt planes: one 2T-item sequence, identical targets for all three
  if (t < 2 * T) {
    const int tg = s_tgt2[t];
    if (tg >= 0) {
      bool alive = true;
      for (int j = t + 1; j < 2 * T; ++j) alive &= (s_tgt2[j] != tg);
      if (alive) {
        const int u = (t < T) ? t : (t - T);
        const float vxy = (t < T) ? s_vx[u] : s_vy[u];
        const float vwh = (t < T) ? s_vw[u] : s_vh[u];
        out[O_XY + (long)b * CH2 + tg] = vxy;
        out[O_WH + (long)b * CH2 + tg] = vwh;
        out[O_WT + (long)b * CH2 + tg] = s_vwt[u];
      }
    }
  }
  // obj planes: one T-item sequence, identical targets for all three
  if (t < T) {
    const int tg = s_tgtO[t];
    bool alive = true;
    for (int j = t + 1; j < T; ++j) alive &= (s_tgtO[j] != tg);
    if (alive) {
      out[O_OBJ + (long)b * N + tg] = s_vobj[t];
      out[O_NOOBJ + (long)b * N + tg] = s_vnoobj[t];
      out[O_LABEL + (long)b * N + tg] = s_cls[t];
    }
  }
}

extern "C" void kernel_launch(void* const* d_in, const int* in_sizes, int n_in,
                              void* d_out, int out_size, void* d_ws,
                              size_t ws_size, hipStream_t stream) {
  const float* xy = (const float*)d_in[0];
  const float* wh = (const float*)d_in[1];
  const float* obj = (const float*)d_in[2];
  const float* truth = (const float*)d_in[3];
  const float* biases = (const float*)d_in[4];
  float* out = (float*)d_out;
  float* ws = (float*)d_ws;
  region_k0<<<(B * T + 255) / 256, 256, 0, stream>>>(truth, ws);
  dim3 g1((N + 255) / 256, B);
  region_k1<<<g1, 256, 0, stream>>>(xy, wh, obj, truth, biases, ws, out);
  region_k2<<<B, 128, 0, stream>>>(xy, wh, obj, truth, biases, out);
}

// Round 4
// 113.236 us; speedup vs baseline: 1.0073x; 1.0073x over previous
//
#include <hip/hip_runtime.h>
#include <math.h>

namespace {
constexpr int B = 64, A = 5, H = 52, W = 52, T = 50;
constexpr int HW = H * W;        // 2704
constexpr int N = A * HW;        // 13520
constexpr int CH2 = 2 * A * HW;  // 27040 (per-batch xy/wh/weight span)
constexpr float POS_THRESH_F = 0.6f;
constexpr float EPS_F = 1e-5f;
constexpr int GPB = (HW / 4) * A;  // 3380 groups of 4 boxes per batch
constexpr int GPA = HW / 4;        // 676 groups per anchor

// d_out layout: t_xy, t_wh, t_xywh_weight, t_o_obj, t_o_noobj, t_label (f32)
constexpr long O_XY = 0;
constexpr long O_WH = (long)B * CH2;
constexpr long O_WT = 2L * B * CH2;
constexpr long O_OBJ = 3L * B * CH2;
constexpr long O_NOOBJ = O_OBJ + (long)B * N;
constexpr long O_LABEL = O_NOOBJ + (long)B * N;
}  // namespace

// Kernel 1: per predicted box, "any IoU > 0.6?" over 50 truths -> t_o_noobj
// mask; also writes the base values of all six outputs. 4 boxes/thread along
// r (W%4==0 and HW%4==0 => a group never crosses a row or anchor boundary),
// so all global I/O is aligned float4. Truth boxes staged once in LDS;
// inner-loop reads are wave-broadcast (conflict-free), amortized over 4 boxes.
// Division-free band test (iou>0.6 <=> ov>0.375*(barea+ta)); boxes whose
// decision lands inside the conservative band rerun the exact IEEE-division
// loop so boundary decisions are bit-identical to the reference.
__global__ __launch_bounds__(256) void region_k1(
    const float* __restrict__ xy, const float* __restrict__ wh,
    const float* __restrict__ obj, const float* __restrict__ truth,
    const float* __restrict__ biases, float* __restrict__ out) {
#pragma clang fp contract(off)
  __shared__ float4 s_box[T];  // {tl, tt, tr, tb}
  __shared__ float s_ta[T];    // tw*th (exact)
  const int b = blockIdx.y;
  const int tid = threadIdx.x;
  if (tid < T) {
    const float* t5 = truth + ((long)b * T + tid) * 5;
    const float tx = t5[0], ty = t5[1], tw = t5[2], th = t5[3];
    s_box[tid] = make_float4(tx - tw * 0.5f, ty - th * 0.5f,
                             tx + tw * 0.5f, ty + th * 0.5f);
    s_ta[tid] = tw * th;
  }
  __syncthreads();
  const int g = blockIdx.x * 256 + tid;
  if (g >= GPB) return;
  const int a = g / GPA;
  const int rg = g - a * GPA;
  const int r = rg * 4;         // 4 consecutive boxes, same row, same anchor
  const int h = r / W;
  const int w0 = r - h * W;
  const long pb = (long)b * CH2;
  const long ix = pb + (long)a * HW + r;  // channel a (x / w-part)
  const long iy = ix + (long)A * HW;      // channel a+A (y / h-part)
  const long io = (long)b * N + (long)a * HW + r;
  const float4 x4 = *(const float4*)(xy + ix);
  const float4 y4 = *(const float4*)(xy + iy);
  const float4 wx4 = *(const float4*)(wh + ix);
  const float4 wy4 = *(const float4*)(wh + iy);
  const float4 ob4 = *(const float4*)(obj + io);
  const float ba0 = biases[2 * a], ba1 = biases[2 * a + 1];
  // per-box setup — mirror reference f32 op order exactly
  float bl[4], br[4], bt[4], bb[4], barea[4];
  {
    const float xs[4] = {x4.x, x4.y, x4.z, x4.w};
    const float ys[4] = {y4.x, y4.y, y4.z, y4.w};
    const float wxs[4] = {wx4.x, wx4.y, wx4.z, wx4.w};
    const float wys[4] = {wy4.x, wy4.y, wy4.z, wy4.w};
#pragma unroll
    for (int i = 0; i < 4; ++i) {
      const float bx = (xs[i] + (float)(w0 + i)) / (float)W;
      const float by = (ys[i] + (float)h) / (float)H;
      const float bw = expf(wxs[i]) * ba0 / (float)W;
      const float bh = expf(wys[i]) * ba1 / (float)H;
      bl[i] = bx - bw * 0.5f;
      br[i] = bx + bw * 0.5f;
      bt[i] = by - bh * 0.5f;
      bb[i] = by + bh * 0.5f;
      barea[i] = bw * bh;
    }
  }
  float m1[4] = {-INFINITY, -INFINITY, -INFINITY, -INFINITY};
  float m2[4] = {-INFINITY, -INFINITY, -INFINITY, -INFINITY};
#pragma unroll 5
  for (int t = 0; t < T; ++t) {
    const float4 b4 = s_box[t];
    const float ta = s_ta[t];
#pragma unroll
    for (int i = 0; i < 4; ++i) {
      float ow = fminf(br[i], b4.z) - fmaxf(bl[i], b4.x);
      float oh = fminf(bb[i], b4.w) - fmaxf(bt[i], b4.y);
      ow = fmaxf(ow, 0.0f);
      oh = fmaxf(oh, 0.0f);
      const float ov = ow * oh;
      const float sum = barea[i] + ta;          // > 0 always (barea = exp*exp)
      const float dd = fmaf(-0.375f, sum, ov);  // ov - 0.375*(barea+ta)
      const float tol = 1e-5f * sum;            // band ~74x transform error
      m1[i] = fmaxf(m1[i], dd - tol);
      m2[i] = fmaxf(m2[i], dd + tol);
    }
  }
  float4 noo;
  float hit[4];
#pragma unroll
  for (int i = 0; i < 4; ++i) {
    bool hh = m1[i] > 0.0f;
    if (!hh && m2[i] >= 0.0f) {
      // exact fallback — identical op sequence to the reference
      float m = -INFINITY;
      for (int t = 0; t < T; ++t) {
        const float4 b4 = s_box[t];
        float ow = fminf(br[i], b4.z) - fmaxf(bl[i], b4.x);
        float oh = fminf(bb[i], b4.w) - fmaxf(bt[i], b4.y);
        ow = fmaxf(ow, 0.0f);
        oh = fmaxf(oh, 0.0f);
        const float ov = ow * oh;
        const float iou = ov / ((barea[i] + s_ta[t]) - ov);
        m = fmaxf(m, iou);
      }
      hh = m > POS_THRESH_F;
    }
    hit[i] = hh ? 1.0f : 0.0f;
  }
  noo = make_float4(hit[0] * ob4.x, hit[1] * ob4.y, hit[2] * ob4.z,
                    hit[3] * ob4.w);
  *(float4*)(out + O_NOOBJ + io) = noo;
  *(float4*)(out + O_OBJ + io) = ob4;
  *(float4*)(out + O_LABEL + io) = make_float4(-1.f, -1.f, -1.f, -1.f);
  *(float4*)(out + O_XY + ix) = x4;
  *(float4*)(out + O_XY + iy) = y4;
  *(float4*)(out + O_WH + ix) = wx4;
  *(float4*)(out + O_WH + iy) = wy4;
  *(float4*)(out + O_WT + ix) = make_float4(0.f, 0.f, 0.f, 0.f);
  *(float4*)(out + O_WT + iy) = make_float4(0.f, 0.f, 0.f, 0.f);
}

// Kernel 2: per-batch truth scatters with exact JAX .at[] semantics:
//  - negative index (-1) wraps to the last element (JAX normalizes before drop)
//  - lin1 with channel 2*tn+A >= 2A is genuinely OOB -> dropped
//  - duplicate targets: last write (ascending t, lin0-scatter before
//    lin1-scatter) wins — parallel "am I the last writer?" checks.
__global__ __launch_bounds__(128) void region_k2(
    const float* __restrict__ xy, const float* __restrict__ wh,
    const float* __restrict__ obj, const float* __restrict__ truth,
    const float* __restrict__ biases, float* __restrict__ out) {
#pragma clang fp contract(off)
  __shared__ float s_vx[T], s_vy[T], s_vw[T], s_vh[T], s_vwt[T];
  __shared__ float s_vobj[T], s_vnoobj[T], s_cls[T];
  __shared__ int s_cell[T], s_eff[T], s_lin0[T], s_lin1[T], s_tn[T], s_win[T];
  __shared__ int s_tgt2[2 * T];  // xy/wh/wt-plane scatter sequence (-2 = drop)
  __shared__ int s_tgtO[T];      // obj-plane scatter sequence
  const int b = blockIdx.x;
  const int t = threadIdx.x;
  if (t < T) {
    const float* t5 = truth + ((long)b * T + t) * 5;
    const float tx = t5[0], ty = t5[1], tw = t5[2], th = t5[3];
    s_cls[t] = t5[4];
    int ti = (int)(tx * (float)W);  // trunc, matches astype(int32)
    int tj = (int)(ty * (float)H);
    int tn = 0;
    float best = -INFINITY;
    for (int aa = 0; aa < A; ++aa) {
      const float bwa = biases[2 * aa] / (float)W;
      const float bha = biases[2 * aa + 1] / (float)H;
      const float num = fminf(tw, bwa) * fminf(th, bha);
      const float den = fmaxf(tw, bwa) * fmaxf(th, bha) + EPS_F;
      const float rr = num / den;
      if (rr > best) { best = rr; tn = aa; }  // first-max, like jnp.argmax
    }
    if (tw <= EPS_F || th <= EPS_F) { ti = -1; tj = -1; tn = -1; }
    const bool valid = ti >= 0;
    const int cell = valid ? (tn * H + tj) * W + ti : -1;
    s_cell[t] = cell;
    s_eff[t] = valid ? cell : (N - 1);  // -1 wraps to N-1 in winner scatter
    const int nc = tn < 0 ? 0 : tn, jc = tj < 0 ? 0 : tj, ic = ti < 0 ? 0 : ti;
    s_tn[t] = tn;
    s_lin0[t] = (2 * tn * H + tj) * W + ti;        // only used when win
    s_lin1[t] = ((2 * tn + A) * H + tj) * W + ti;  // only used when win
    s_vx[t] = tx * (float)W - (float)ic;
    s_vy[t] = ty * (float)H - (float)jc;
    s_vw[t] = logf(fmaxf(tw * (float)W / biases[2 * nc], 1e-12f));
    s_vh[t] = logf(fmaxf(th * (float)H / biases[2 * nc + 1], 1e-12f));
    s_vwt[t] = 2.0f - tw * th;  // COORD_SCALE = 1
    // v_obj = IoU of predicted box at (nc,jc,ic) vs this truth (RESCORE)
    const long rr2 = (long)nc * HW + (long)jc * W + ic;
    const long pb = (long)b * CH2;
    const float x = xy[pb + rr2], y = xy[pb + (long)A * HW + rr2];
    const float wx = wh[pb + rr2], wyv = wh[pb + (long)A * HW + rr2];
    s_vnoobj[t] = obj[(long)b * N + rr2];
    const float bx = (x + (float)ic) / (float)W;
    const float by = (y + (float)jc) / (float)H;
    const float bw = expf(wx) * biases[2 * nc] / (float)W;
    const float bh = expf(wyv) * biases[2 * nc + 1] / (float)H;
    float ow = fminf(bx + bw * 0.5f, tx + tw * 0.5f) -
               fmaxf(bx - bw * 0.5f, tx - tw * 0.5f);
    float oh = fminf(by + bh * 0.5f, ty + th * 0.5f) -
               fmaxf(by - bh * 0.5f, ty - th * 0.5f);
    ow = fmaxf(ow, 0.0f);
    oh = fmaxf(oh, 0.0f);
    const float ov = ow * oh;
    s_vobj[t] = ov / (((bw * bh) + tw * th) - ov);
  }
  __syncthreads();
  if (t < T) {
    int winf = 0;
    if (s_cell[t] >= 0) {  // valid
      winf = 1;
      for (int u = t + 1; u < T; ++u)
        if (s_eff[u] == s_cell[t]) { winf = 0; break; }  // higher t wins
    }
    s_win[t] = winf;
  }
  __syncthreads();
  if (t < T) {
    const int J = CH2 - 1;  // wrapped target of index -1 in 2A*H*W space
    int tgt0, tgt1;
    if (s_win[t]) {
      tgt0 = s_lin0[t];
      tgt1 = (2 * s_tn[t] + A < 2 * A) ? s_lin1[t] : -2;  // OOB -> dropped
    } else {
      tgt0 = J;  // -1 wraps
      tgt1 = J;
    }
    s_tgt2[t] = tgt0;
    s_tgt2[T + t] = tgt1;
    s_tgtO[t] = s_win[t] ? s_cell[t] : (N - 1);
  }
  __syncthreads();
  // xy/wh/wt planes: one 2T-item sequence, identical targets for all three
  if (t < 2 * T) {
    const int tg = s_tgt2[t];
    if (tg >= 0) {
      bool alive = true;
      for (int j = t + 1; j < 2 * T; ++j) alive &= (s_tgt2[j] != tg);
      if (alive) {
        const int u = (t < T) ? t : (t - T);
        const float vxy = (t < T) ? s_vx[u] : s_vy[u];
        const float vwh = (t < T) ? s_vw[u] : s_vh[u];
        out[O_XY + (long)b * CH2 + tg] = vxy;
        out[O_WH + (long)b * CH2 + tg] = vwh;
        out[O_WT + (long)b * CH2 + tg] = s_vwt[u];
      }
    }
  }
  // obj planes: one T-item sequence, identical targets for all three
  if (t < T) {
    const int tg = s_tgtO[t];
    bool alive = true;
    for (int j = t + 1; j < T; ++j) alive &= (s_tgtO[j] != tg);
    if (alive) {
      out[O_OBJ + (long)b * N + tg] = s_vobj[t];
      out[O_NOOBJ + (long)b * N + tg] = s_vnoobj[t];
      out[O_LABEL + (long)b * N + tg] = s_cls[t];
    }
  }
}

extern "C" void kernel_launch(void* const* d_in, const int* in_sizes, int n_in,
                              void* d_out, int out_size, void* d_ws,
                              size_t ws_size, hipStream_t stream) {
  const float* xy = (const float*)d_in[0];
  const float* wh = (const float*)d_in[1];
  const float* obj = (const float*)d_in[2];
  const float* truth = (const float*)d_in[3];
  const float* biases = (const float*)d_in[4];
  float* out = (float*)d_out;
  dim3 g1((GPB + 255) / 256, B);
  region_k1<<<g1, 256, 0, stream>>>(xy, wh, obj, truth, biases, out);
  region_k2<<<B, 128, 0, stream>>>(xy, wh, obj, truth, biases, out);
}

// Round 5
// 108.727 us; speedup vs baseline: 1.0490x; 1.0415x over previous
//
#include <hip/hip_runtime.h>
#include <math.h>

namespace {
constexpr int B = 64, A = 5, H = 52, W = 52, T = 50;
constexpr int HW = H * W;        // 2704
constexpr int N = A * HW;        // 13520
constexpr int CH2 = 2 * A * HW;  // 27040 (per-batch xy/wh/weight span)
constexpr float POS_THRESH_F = 0.6f;
constexpr float EPS_F = 1e-5f;

// d_out layout: t_xy, t_wh, t_xywh_weight, t_o_obj, t_o_noobj, t_label (f32)
constexpr long O_XY = 0;
constexpr long O_WH = (long)B * CH2;
constexpr long O_WT = 2L * B * CH2;
constexpr long O_OBJ = 3L * B * CH2;
constexpr long O_NOOBJ = O_OBJ + (long)B * N;
constexpr long O_LABEL = O_NOOBJ + (long)B * N;
}  // namespace

// Kernel 1 (round-2 winner, reverted): per predicted box, "any IoU > 0.6?"
// over 50 truths -> t_o_noobj mask; also writes the base values of all six
// outputs. Truth boxes staged in LDS (wave-broadcast reads, conflict-free).
// Division-free test (iou>0.6 <=> ov>0.375*(barea+ta)) with a conservative
// tolerance band; band threads rerun the exact IEEE-division loop so boundary
// decisions are bit-identical to the reference (validated absmax 0.0 x3).
__global__ __launch_bounds__(256) void region_k1(
    const float* __restrict__ xy, const float* __restrict__ wh,
    const float* __restrict__ obj, const float* __restrict__ truth,
    const float* __restrict__ biases, float* __restrict__ out) {
#pragma clang fp contract(off)
  __shared__ float4 s_box[T];  // {tl, tt, tr, tb}
  __shared__ float s_ta375[T];
  __shared__ float s_ta[T];
  const int b = blockIdx.y;
  const int tid = threadIdx.x;
  if (tid < T) {
    const float* t5 = truth + ((long)b * T + tid) * 5;
    const float tx = t5[0], ty = t5[1], tw = t5[2], th = t5[3];
    s_box[tid] = make_float4(tx - tw * 0.5f, ty - th * 0.5f,
                             tx + tw * 0.5f, ty + th * 0.5f);
    const float ta = tw * th;
    s_ta[tid] = ta;
    s_ta375[tid] = 0.375f * ta;
  }
  __syncthreads();
  const int n = blockIdx.x * 256 + tid;
  if (n >= N) return;
  const int a = n / HW;
  const int r = n - a * HW;
  const int h = r / W;
  const int w = r - h * W;
  const long pb = (long)b * CH2;
  const long ix = pb + (long)a * HW + r;  // channel a (x / w-part)
  const long iy = ix + (long)A * HW;      // channel a+A (y / h-part)
  const float x = xy[ix], y = xy[iy];
  const float wx = wh[ix], wyv = wh[iy];
  const long io = (long)b * N + n;
  const float objv = obj[io];
  // box center/size — mirror reference f32 op order exactly
  const float bx = (x + (float)w) / (float)W;
  const float by = (y + (float)h) / (float)H;
  const float bw = expf(wx) * biases[2 * a] / (float)W;
  const float bh = expf(wyv) * biases[2 * a + 1] / (float)H;
  const float bl = bx - bw * 0.5f, brr = bx + bw * 0.5f;
  const float bt = by - bh * 0.5f, bbt = by + bh * 0.5f;
  const float barea = bw * bh;
  const float tb375 = 0.375f * barea;
  bool hit = false, nearb = false;
#pragma unroll 10
  for (int t = 0; t < T; ++t) {
    const float4 b4 = s_box[t];
    float ow = fminf(brr, b4.z) - fmaxf(bl, b4.x);
    float oh = fminf(bbt, b4.w) - fmaxf(bt, b4.y);
    ow = fmaxf(ow, 0.0f);
    oh = fmaxf(oh, 0.0f);
    const float ov = ow * oh;
    const float rhs = tb375 + s_ta375[t];  // 0.375*(barea+ta) (approx)
    const float dd = ov - rhs;
    const float tol = 2.6667e-5f * rhs;  // ~1e-5 * (barea+ta): >>2ulp band
    hit = hit || (dd > tol);
    nearb = nearb || (fabsf(dd) <= tol);
  }
  if (nearb && !hit) {
    // exact fallback — identical op sequence to the reference
    float m = -INFINITY;
    for (int t = 0; t < T; ++t) {
      const float4 b4 = s_box[t];
      float ow = fminf(brr, b4.z) - fmaxf(bl, b4.x);
      float oh = fminf(bbt, b4.w) - fmaxf(bt, b4.y);
      ow = fmaxf(ow, 0.0f);
      oh = fmaxf(oh, 0.0f);
      const float ov = ow * oh;
      const float iou = ov / ((barea + s_ta[t]) - ov);
      m = fmaxf(m, iou);
    }
    hit = m > POS_THRESH_F;
  }
  out[O_NOOBJ + io] = hit ? objv : 0.0f;
  out[O_OBJ + io] = objv;
  out[O_LABEL + io] = -1.0f;
  out[O_XY + ix] = x;
  out[O_XY + iy] = y;
  out[O_WH + ix] = wx;
  out[O_WH + iy] = wyv;
  out[O_WT + ix] = 0.0f;
  out[O_WT + iy] = 0.0f;
}

// Kernel 2: per-batch truth scatters with exact JAX .at[] semantics:
//  - negative index (-1) wraps to the last element (JAX normalizes before drop)
//  - lin1 with channel 2*tn+A >= 2A is genuinely OOB -> dropped
//  - duplicate targets: last write (ascending t, lin0-scatter before
//    lin1-scatter) wins — parallel "am I the last writer?" checks.
__global__ __launch_bounds__(128) void region_k2(
    const float* __restrict__ xy, const float* __restrict__ wh,
    const float* __restrict__ obj, const float* __restrict__ truth,
    const float* __restrict__ biases, float* __restrict__ out) {
#pragma clang fp contract(off)
  __shared__ float s_vx[T], s_vy[T], s_vw[T], s_vh[T], s_vwt[T];
  __shared__ float s_vobj[T], s_vnoobj[T], s_cls[T];
  __shared__ int s_cell[T], s_eff[T], s_lin0[T], s_lin1[T], s_tn[T], s_win[T];
  __shared__ int s_tgt2[2 * T];  // xy/wh/wt-plane scatter sequence (-2 = drop)
  __shared__ int s_tgtO[T];      // obj-plane scatter sequence
  const int b = blockIdx.x;
  const int t = threadIdx.x;
  if (t < T) {
    const float* t5 = truth + ((long)b * T + t) * 5;
    const float tx = t5[0], ty = t5[1], tw = t5[2], th = t5[3];
    s_cls[t] = t5[4];
    int ti = (int)(tx * (float)W);  // trunc, matches astype(int32)
    int tj = (int)(ty * (float)H);
    int tn = 0;
    float best = -INFINITY;
    for (int aa = 0; aa < A; ++aa) {
      const float bwa = biases[2 * aa] / (float)W;
      const float bha = biases[2 * aa + 1] / (float)H;
      const float num = fminf(tw, bwa) * fminf(th, bha);
      const float den = fmaxf(tw, bwa) * fmaxf(th, bha) + EPS_F;
      const float rr = num / den;
      if (rr > best) { best = rr; tn = aa; }  // first-max, like jnp.argmax
    }
    if (tw <= EPS_F || th <= EPS_F) { ti = -1; tj = -1; tn = -1; }
    const bool valid = ti >= 0;
    const int cell = valid ? (tn * H + tj) * W + ti : -1;
    s_cell[t] = cell;
    s_eff[t] = valid ? cell : (N - 1);  // -1 wraps to N-1 in winner scatter
    const int nc = tn < 0 ? 0 : tn, jc = tj < 0 ? 0 : tj, ic = ti < 0 ? 0 : ti;
    s_tn[t] = tn;
    s_lin0[t] = (2 * tn * H + tj) * W + ti;        // only used when win
    s_lin1[t] = ((2 * tn + A) * H + tj) * W + ti;  // only used when win
    s_vx[t] = tx * (float)W - (float)ic;
    s_vy[t] = ty * (float)H - (float)jc;
    s_vw[t] = logf(fmaxf(tw * (float)W / biases[2 * nc], 1e-12f));
    s_vh[t] = logf(fmaxf(th * (float)H / biases[2 * nc + 1], 1e-12f));
    s_vwt[t] = 2.0f - tw * th;  // COORD_SCALE = 1
    // v_obj = IoU of predicted box at (nc,jc,ic) vs this truth (RESCORE)
    const long rr2 = (long)nc * HW + (long)jc * W + ic;
    const long pb = (long)b * CH2;
    const float x = xy[pb + rr2], y = xy[pb + (long)A * HW + rr2];
    const float wx = wh[pb + rr2], wyv = wh[pb + (long)A * HW + rr2];
    s_vnoobj[t] = obj[(long)b * N + rr2];
    const float bx = (x + (float)ic) / (float)W;
    const float by = (y + (float)jc) / (float)H;
    const float bw = expf(wx) * biases[2 * nc] / (float)W;
    const float bh = expf(wyv) * biases[2 * nc + 1] / (float)H;
    float ow = fminf(bx + bw * 0.5f, tx + tw * 0.5f) -
               fmaxf(bx - bw * 0.5f, tx - tw * 0.5f);
    float oh = fminf(by + bh * 0.5f, ty + th * 0.5f) -
               fmaxf(by - bh * 0.5f, ty - th * 0.5f);
    ow = fmaxf(ow, 0.0f);
    oh = fmaxf(oh, 0.0f);
    const float ov = ow * oh;
    s_vobj[t] = ov / (((bw * bh) + tw * th) - ov);
  }
  __syncthreads();
  if (t < T) {
    int winf = 0;
    if (s_cell[t] >= 0) {  // valid
      winf = 1;
      for (int u = t + 1; u < T; ++u)
        if (s_eff[u] == s_cell[t]) { winf = 0; break; }  // higher t wins
    }
    s_win[t] = winf;
  }
  __syncthreads();
  if (t < T) {
    const int J = CH2 - 1;  // wrapped target of index -1 in 2A*H*W space
    int tgt0, tgt1;
    if (s_win[t]) {
      tgt0 = s_lin0[t];
      tgt1 = (2 * s_tn[t] + A < 2 * A) ? s_lin1[t] : -2;  // OOB -> dropped
    } else {
      tgt0 = J;  // -1 wraps
      tgt1 = J;
    }
    s_tgt2[t] = tgt0;
    s_tgt2[T + t] = tgt1;
    s_tgtO[t] = s_win[t] ? s_cell[t] : (N - 1);
  }
  __syncthreads();
  // xy/wh/wt planes: one 2T-item sequence, identical targets for all three
  if (t < 2 * T) {
    const int tg = s_tgt2[t];
    if (tg >= 0) {
      bool alive = true;
      for (int j = t + 1; j < 2 * T; ++j) alive &= (s_tgt2[j] != tg);
      if (alive) {
        const int u = (t < T) ? t : (t - T);
        const float vxy = (t < T) ? s_vx[u] : s_vy[u];
        const float vwh = (t < T) ? s_vw[u] : s_vh[u];
        out[O_XY + (long)b * CH2 + tg] = vxy;
        out[O_WH + (long)b * CH2 + tg] = vwh;
        out[O_WT + (long)b * CH2 + tg] = s_vwt[u];
      }
    }
  }
  // obj planes: one T-item sequence, identical targets for all three
  if (t < T) {
    const int tg = s_tgtO[t];
    bool alive = true;
    for (int j = t + 1; j < T; ++j) alive &= (s_tgtO[j] != tg);
    if (alive) {
      out[O_OBJ + (long)b * N + tg] = s_vobj[t];
      out[O_NOOBJ + (long)b * N + tg] = s_vnoobj[t];
      out[O_LABEL + (long)b * N + tg] = s_cls[t];
    }
  }
}

extern "C" void kernel_launch(void* const* d_in, const int* in_sizes, int n_in,
                              void* d_out, int out_size, void* d_ws,
                              size_t ws_size, hipStream_t stream) {
  const float* xy = (const float*)d_in[0];
  const float* wh = (const float*)d_in[1];
  const float* obj = (const float*)d_in[2];
  const float* truth = (const float*)d_in[3];
  const float* biases = (const float*)d_in[4];
  float* out = (float*)d_out;
  dim3 g1((N + 255) / 256, B);
  region_k1<<<g1, 256, 0, stream>>>(xy, wh, obj, truth, biases, out);
  region_k2<<<B, 128, 0, stream>>>(xy, wh, obj, truth, biases, out);
}